// Round 3
// baseline (78.424 us; speedup 1.0000x reference)
//
#include <hip/hip_runtime.h>
#include <math.h>

// L=13, M=12, ODD_KS=(1,3,5) -> NK=3
// Register-blocked: each thread computes 4 consecutive outputs, so every
// wave-uniform coefficient broadcast (ds_read_b128) feeds 12 FMAs instead
// of 3 -> conv goes from LDS-issue-bound (~15us/CU) to ~4us/CU.
// Reduction split 2 ways: waves {0,1} do the B/A table, waves {2,3} the C
// table; partials combined through LDS.
// Power/sample arrays are phase-split [4][WIN/4] (sample j at [j&3][j>>2])
// so 4-consecutive-output reads are lane-contiguous (no 8-way conflicts)
// and the (r,d) reads collapse to 28 unique, hoisted to registers.
#define LL    13
#define MM    12
#define NKK   3
#define OUTS  512                 // outputs per block
#define BLOCK 256                 // 4 waves
#define HALO  24
#define WIN   (OUTS + 2*HALO)     // 560
#define WIN4  (WIN/4)             // 140
#define NWB   (25 * LL)           // 325: B/A quads, d-major (A at m==12)
#define NWC   (24 * LL)           // 312: C quads, d-major (m<12)

__global__ __launch_bounds__(BLOCK)
void gmp_kernel(const float* __restrict__ x,    // (B,T,2)
                const float* __restrict__ Ac,   // (L,NK)
                const float* __restrict__ Bc,   // (L,M,NK)
                const float* __restrict__ Cc,   // (L,M,NK)
                float* __restrict__ out,        // (B,T,2)
                int T, int tilesPerB)
{
    __shared__ float2 sPa[4][WIN4];   // {a, a^3}   sample j -> [j&3][j>>2]
    __shared__ float  sPb[4][WIN4];   // a^5
    __shared__ float2 sZ4[4][WIN4];   // {re, im}
    __shared__ float4 sWB[NWB];       // B/A coefficient quads (broadcast)
    __shared__ float4 sWC[NWC];       // C coefficient quads (broadcast)
    __shared__ float2 sAcc[2][OUTS];  // per-role partial sums

    const int tid = threadIdx.x;
    const int b   = blockIdx.x / tilesPerB;
    const int t0  = (blockIdx.x % tilesPerB) * OUTS;

    const float* xb = x + (size_t)b * T * 2;

    // --- Stage 560-sample window (circular wrap), phase-split layout ---
    for (int j = tid; j < WIN; j += BLOCK) {
        int t = t0 - HALO + j;
        if (t < 0)  t += T;
        if (t >= T) t -= T;
        const float2 z = *(const float2*)(xb + 2 * t);
        float a2 = z.x * z.x + z.y * z.y;
        float a  = sqrtf(a2);
        sZ4[j & 3][j >> 2] = z;
        sPa[j & 3][j >> 2] = make_float2(a, a * a2);
        sPb[j & 3][j >> 2] = a * a2 * a2;
    }

    // --- Stage coefficient tables (d-major quads; invalid slots = 0) ---
    for (int idx = tid; idx < NWB; idx += BLOCK) {
        const int d = idx / LL;
        const int l = idx - d * LL;
        const int m = d - l;
        float4 w = make_float4(0.f, 0.f, 0.f, 0.f);
        if (m >= 0 && m <= MM) {
            const float* s = (m == MM) ? (Ac + l * NKK)
                                       : (Bc + (l * MM + m) * NKK);
            w = make_float4(s[0], s[1], s[2], 0.f);
        }
        sWB[idx] = w;
    }
    for (int idx = tid; idx < NWC; idx += BLOCK) {
        const int d = idx / LL;
        const int l = idx - d * LL;
        const int m = d - l;
        float4 w = make_float4(0.f, 0.f, 0.f, 0.f);
        if (m >= 0 && m < MM) {
            const float* s = Cc + (l * MM + m) * NKK;
            w = make_float4(s[0], s[1], s[2], 0.f);
        }
        sWC[idx] = w;
    }
    __syncthreads();

    const int g     = tid & 127;      // index within role group
    const int roleC = tid >> 7;       // 0: B/A table, 1: C table
    const int o0    = g * 4;          // 4 consecutive outputs

    float cc[4][LL];
    #pragma unroll
    for (int r = 0; r < 4; ++r)
        #pragma unroll
        for (int l = 0; l < LL; ++l) cc[r][l] = 0.f;

    float sr[4], si[4];

    if (roleC == 0) {
        // Powers for window j = o0 + k, k = r + d in [0,27]
        float2 pa[28]; float pb[28];
        #pragma unroll
        for (int k = 0; k < 28; ++k) {
            pa[k] = sPa[k & 3][g + (k >> 2)];
            pb[k] = sPb[k & 3][g + (k >> 2)];
        }
        #pragma unroll
        for (int d = 0; d < 25; ++d) {
            #pragma unroll
            for (int l = 0; l < LL; ++l) {
                const int m = d - l;
                if (m >= 0 && m <= MM) {          // compile-time fold
                    const float4 w = sWB[d * LL + l];
                    #pragma unroll
                    for (int r = 0; r < 4; ++r) {
                        cc[r][l] += w.x * pa[d + r].x
                                  + w.y * pa[d + r].y
                                  + w.z * pb[d + r];
                    }
                }
            }
        }
        // Epilogue: weight by x1 at window j = o0 + 12 + (r + l)
        float2 zw[16];
        #pragma unroll
        for (int k = 0; k < 16; ++k)
            zw[k] = sZ4[k & 3][g + 3 + (k >> 2)];
        #pragma unroll
        for (int r = 0; r < 4; ++r) {
            sr[r] = 0.f; si[r] = 0.f;
            #pragma unroll
            for (int l = 0; l < LL; ++l) {
                const float2 z = zw[r + l];
                sr[r] += z.x * cc[r][l];
                si[r] += z.y * cc[r][l];
            }
        }
    } else {
        // Powers for window j = o0 + 24 + k, k = r + d in [0,26]
        float2 pa[27]; float pb[27];
        #pragma unroll
        for (int k = 0; k < 27; ++k) {
            pa[k] = sPa[k & 3][g + 6 + (k >> 2)];
            pb[k] = sPb[k & 3][g + 6 + (k >> 2)];
        }
        #pragma unroll
        for (int d = 0; d < 24; ++d) {
            #pragma unroll
            for (int l = 0; l < LL; ++l) {
                const int m = d - l;
                if (m >= 0 && m < MM) {           // compile-time fold
                    const float4 w = sWC[d * LL + l];
                    #pragma unroll
                    for (int r = 0; r < 4; ++r) {
                        cc[r][l] += w.x * pa[d + r].x
                                  + w.y * pa[d + r].y
                                  + w.z * pb[d + r];
                    }
                }
            }
        }
        // Epilogue: weight by x3_last at window j = o0 + 36 + (r + l)
        float2 zw[16];
        #pragma unroll
        for (int k = 0; k < 16; ++k)
            zw[k] = sZ4[k & 3][g + 9 + (k >> 2)];
        #pragma unroll
        for (int r = 0; r < 4; ++r) {
            sr[r] = 0.f; si[r] = 0.f;
            #pragma unroll
            for (int l = 0; l < LL; ++l) {
                const float2 z = zw[r + l];
                sr[r] += z.x * cc[r][l];
                si[r] += z.y * cc[r][l];
            }
        }
    }

    #pragma unroll
    for (int r = 0; r < 4; ++r)
        sAcc[roleC][o0 + r] = make_float2(sr[r], si[r]);
    __syncthreads();

    // --- Combine role partials and store (lane-contiguous b64) ---
    #pragma unroll
    for (int s = 0; s < 2; ++s) {
        const int j = tid + s * BLOCK;
        const float2 a0 = sAcc[0][j];
        const float2 a1 = sAcc[1][j];
        const int t = t0 + j;
        if (t < T) {
            float2* op = (float2*)(out + ((size_t)b * T + t) * 2);
            *op = make_float2(a0.x + a1.x, a0.y + a1.y);
        }
    }
}

extern "C" void kernel_launch(void* const* d_in, const int* in_sizes, int n_in,
                              void* d_out, int out_size, void* d_ws, size_t ws_size,
                              hipStream_t stream)
{
    // Inputs: x (B,T,2) f32, h_0 (B,16) f32 [unused], A_kl (L,NK),
    // B_klm (L,M,NK), C_klm (L,M,NK)
    const float* x  = (const float*)d_in[0];
    const float* Ac = (const float*)d_in[2];
    const float* Bc = (const float*)d_in[3];
    const float* Cc = (const float*)d_in[4];
    float* out = (float*)d_out;

    const int Bsz = in_sizes[1] / 16;               // h_0 is (B,16)
    const int T   = in_sizes[0] / (2 * Bsz);        // x is (B,T,2)
    const int tilesPerB = (T + OUTS - 1) / OUTS;    // 16 for T=8192

    dim3 grid(Bsz * tilesPerB);                     // 256 blocks (1/CU)
    dim3 block(BLOCK);
    gmp_kernel<<<grid, block, 0, stream>>>(x, Ac, Bc, Cc, out, T, tilesPerB);
}

// Round 4
// 70.126 us; speedup vs baseline: 1.1183x; 1.1183x over previous
//
#include <hip/hip_runtime.h>
#include <math.h>

// L=13, M=12, ODD_KS=(1,3,5) -> NK=3
// Geometry identical to the best kernel (R1): 512 blocks x 256 threads,
// 2 blocks/CU, same 304-sample window + 637-quad coefficient staging.
// Conv changed: 2-way role split (waves 0-1: B/A table, waves 2-3: C table)
// halves per-wave DS traffic; register-blocking R=2 outputs/thread makes
// each wave-uniform coefficient broadcast feed 6 FMAs instead of 3.
// Window arrays phase-split [2][WIN/2] (sample j -> [j&1][j>>1]) so the
// R=2 hoisted power reads are lane-contiguous (2-way bank alias = free).
// Register budget kept small (pa[26]+pb[26]+cc[2][13] ~ 130 VGPR peak,
// __launch_bounds__(256,2)) -- the R3 regression was spill-driven.
#define LL    13
#define MM    12
#define NKK   3
#define OUTS  256                 // outputs per block
#define BLOCK 256                 // 4 waves: 2 per role
#define HALO  24
#define WIN   (OUTS + 2*HALO)     // 304
#define WIN2  (WIN/2)             // 152
#define NWB   (25 * LL)           // 325: B/A quads, d-major (A at m==12)
#define NWC   (24 * LL)           // 312: C quads, d-major (m<12)

__global__ __launch_bounds__(BLOCK, 2)
void gmp_kernel(const float* __restrict__ x,    // (B,T,2)
                const float* __restrict__ Ac,   // (L,NK)
                const float* __restrict__ Bc,   // (L,M,NK)
                const float* __restrict__ Cc,   // (L,M,NK)
                float* __restrict__ out,        // (B,T,2)
                int T, int tilesPerB)
{
    __shared__ float2 sPa[2][WIN2];     // {a, a^3}  sample j -> [j&1][j>>1]
    __shared__ float  sPb[2][WIN2];     // a^5
    __shared__ float2 sZ2[2][WIN2];     // {re, im}
    __shared__ float4 sWB[NWB];         // B/A coefficient quads (broadcast)
    __shared__ float4 sWC[NWC];         // C coefficient quads (broadcast)
    __shared__ float4 sAcc[2][BLOCK/2]; // [role][g] = {sr0,si0,sr1,si1}

    const int tid = threadIdx.x;
    const int b   = blockIdx.x / tilesPerB;
    const int t0  = (blockIdx.x % tilesPerB) * OUTS;

    const float* xb = x + (size_t)b * T * 2;

    // --- Stage 304-sample window (circular wrap), phase-split layout ---
    for (int j = tid; j < WIN; j += BLOCK) {
        int t = t0 - HALO + j;
        if (t < 0)  t += T;
        if (t >= T) t -= T;
        const float2 z = *(const float2*)(xb + 2 * t);
        float a2 = z.x * z.x + z.y * z.y;
        float a  = sqrtf(a2);
        sZ2[j & 1][j >> 1] = z;
        sPa[j & 1][j >> 1] = make_float2(a, a * a2);
        sPb[j & 1][j >> 1] = a * a2 * a2;
    }

    // --- Stage coefficient tables (d-major quads; invalid slots = 0) ---
    for (int idx = tid; idx < NWB; idx += BLOCK) {
        const int d = idx / LL;
        const int l = idx - d * LL;
        const int m = d - l;
        float4 w = make_float4(0.f, 0.f, 0.f, 0.f);
        if (m >= 0 && m <= MM) {
            const float* s = (m == MM) ? (Ac + l * NKK)
                                       : (Bc + (l * MM + m) * NKK);
            w = make_float4(s[0], s[1], s[2], 0.f);
        }
        sWB[idx] = w;
    }
    for (int idx = tid; idx < NWC; idx += BLOCK) {
        const int d = idx / LL;
        const int l = idx - d * LL;
        const int m = d - l;
        float4 w = make_float4(0.f, 0.f, 0.f, 0.f);
        if (m >= 0 && m < MM) {
            const float* s = Cc + (l * MM + m) * NKK;
            w = make_float4(s[0], s[1], s[2], 0.f);
        }
        sWC[idx] = w;
    }
    __syncthreads();

    const int g    = tid & 127;   // thread within role group (2 waves)
    const int role = tid >> 7;    // 0: B/A table, 1: C table (wave-uniform)

    // Thread computes outputs o = 2g and 2g+1 for its half of the reduction.
    float cc[2][LL];
    #pragma unroll
    for (int l = 0; l < LL; ++l) { cc[0][l] = 0.f; cc[1][l] = 0.f; }

    float sr0, si0, sr1, si1;

    if (role == 0) {
        // B/A powers: window j = 2g + k, k = d + r in [0,26)
        float2 pa[26]; float pb[26];
        #pragma unroll
        for (int k = 0; k < 26; ++k) {
            pa[k] = sPa[k & 1][g + (k >> 1)];
            pb[k] = sPb[k & 1][g + (k >> 1)];
        }
        #pragma unroll
        for (int d = 0; d < 25; ++d) {
            #pragma unroll
            for (int l = 0; l < LL; ++l) {
                const int m = d - l;
                if (m >= 0 && m <= MM) {          // compile-time fold
                    const float4 w = sWB[d * LL + l];
                    cc[0][l] += w.x * pa[d  ].x + w.y * pa[d  ].y + w.z * pb[d  ];
                    cc[1][l] += w.x * pa[d+1].x + w.y * pa[d+1].y + w.z * pb[d+1];
                }
            }
        }
        // Epilogue weight x1: window j = 2g + 12 + k', k' = r + l in [0,14)
        float2 zw[14];
        #pragma unroll
        for (int k = 0; k < 14; ++k)
            zw[k] = sZ2[k & 1][g + 6 + (k >> 1)];
        sr0 = si0 = sr1 = si1 = 0.f;
        #pragma unroll
        for (int l = 0; l < LL; ++l) {
            sr0 += zw[l    ].x * cc[0][l];  si0 += zw[l    ].y * cc[0][l];
            sr1 += zw[l + 1].x * cc[1][l];  si1 += zw[l + 1].y * cc[1][l];
        }
    } else {
        // C powers: window j = 2g + 24 + k, k = d + r in [0,25)
        float2 pa[25]; float pb[25];
        #pragma unroll
        for (int k = 0; k < 25; ++k) {
            pa[k] = sPa[k & 1][g + 12 + (k >> 1)];
            pb[k] = sPb[k & 1][g + 12 + (k >> 1)];
        }
        #pragma unroll
        for (int d = 0; d < 24; ++d) {
            #pragma unroll
            for (int l = 0; l < LL; ++l) {
                const int m = d - l;
                if (m >= 0 && m < MM) {           // compile-time fold
                    const float4 w = sWC[d * LL + l];
                    cc[0][l] += w.x * pa[d  ].x + w.y * pa[d  ].y + w.z * pb[d  ];
                    cc[1][l] += w.x * pa[d+1].x + w.y * pa[d+1].y + w.z * pb[d+1];
                }
            }
        }
        // Epilogue weight x3_last: window j = 2g + 36 + k', k' = r + l
        float2 zw[14];
        #pragma unroll
        for (int k = 0; k < 14; ++k)
            zw[k] = sZ2[k & 1][g + 18 + (k >> 1)];
        sr0 = si0 = sr1 = si1 = 0.f;
        #pragma unroll
        for (int l = 0; l < LL; ++l) {
            sr0 += zw[l    ].x * cc[0][l];  si0 += zw[l    ].y * cc[0][l];
            sr1 += zw[l + 1].x * cc[1][l];  si1 += zw[l + 1].y * cc[1][l];
        }
    }

    sAcc[role][g] = make_float4(sr0, si0, sr1, si1);  // b128, lane-contiguous
    __syncthreads();

    // --- Combine role partials and store (lane-contiguous b64) ---
    {
        const float2* p0 = (const float2*)&sAcc[0][0];
        const float2* p1 = (const float2*)&sAcc[1][0];
        const float2 a0 = p0[tid];
        const float2 a1 = p1[tid];
        const int t = t0 + tid;
        if (t < T) {
            float2* op = (float2*)(out + ((size_t)b * T + t) * 2);
            *op = make_float2(a0.x + a1.x, a0.y + a1.y);
        }
    }
}

extern "C" void kernel_launch(void* const* d_in, const int* in_sizes, int n_in,
                              void* d_out, int out_size, void* d_ws, size_t ws_size,
                              hipStream_t stream)
{
    // Inputs: x (B,T,2) f32, h_0 (B,16) f32 [unused], A_kl (L,NK),
    // B_klm (L,M,NK), C_klm (L,M,NK)
    const float* x  = (const float*)d_in[0];
    const float* Ac = (const float*)d_in[2];
    const float* Bc = (const float*)d_in[3];
    const float* Cc = (const float*)d_in[4];
    float* out = (float*)d_out;

    const int Bsz = in_sizes[1] / 16;               // h_0 is (B,16)
    const int T   = in_sizes[0] / (2 * Bsz);        // x is (B,T,2)
    const int tilesPerB = (T + OUTS - 1) / OUTS;    // 32 for T=8192

    dim3 grid(Bsz * tilesPerB);                     // 512 blocks (2/CU)
    dim3 block(BLOCK);
    gmp_kernel<<<grid, block, 0, stream>>>(x, Ac, Bc, Cc, out, T, tilesPerB);
}